// Round 9
// baseline (134.545 us; speedup 1.0000x reference)
//
#include <hip/hip_runtime.h>

#define S 128
#define WPB 4                 // waves per block
#define NBANDS 4              // 8-row bands per wave = 32 rows/wave
#define NBLOCKS 1024          // 4096 waves = 1024 planes x 4 quarters

typedef const __attribute__((address_space(1))) void* gas_t;
typedef __attribute__((address_space(3))) void* las_t;

__global__ __launch_bounds__(256, 3) void pairwise_potential_kernel(
    const float* __restrict__ x, const float* __restrict__ w1,
    const float* __restrict__ w2, float* __restrict__ out)
{
    __shared__ float tile[WPB][2][10][S];     // 2 slices/wave, 40960 B/block

    const int tid = threadIdx.x;
    const int wid = tid >> 6;
    const int l   = tid & 63;
    const int qc  = l & 31;        // quad-column
    const int rg  = l >> 5;        // 0: rows 0-3 of band, 1: rows 4-7

    const int gw      = blockIdx.x * WPB + wid;
    const int plane   = gw >> 2;               // b*64 + c
    const int quarter = gw & 3;
    const int Q0      = quarter * 32;
    const int c       = plane & 63;
    const int col     = qc * 4;

    const float* xp  = x   + ((size_t)plane << 14);
    const float* w1p = w1  + (size_t)c * (S * S);
    const float* w2p = w2  + (size_t)c * (S * S);
    float*       op  = out + ((size_t)plane << 14);

    const float NL  = -0.72134752044f;    // -0.5 * log2(e)
    const float E1N = 0.06739229552f;     // exp(-0.5)/9        (d = 1)
    const float E2N = 0.05478541015f;     // exp(-sqrt2/2)/9    (d = sqrt2)
    const float C9  = 0.11111111111f;     // exp(0)/9           (center term)
    const float W2C = 1.07298380550f;     // (4 + 4*sqrt(2)) / 9

    float m[6][6];
    float4 w1v[4], w2v[4];

#define STAGE(I, BUF)                                                          \
    {                                                                          \
        const int r0_ = Q0 + (I) * 8;                                          \
        const int st_ = min(max(r0_ - 1, 0), S - 10);                          \
        _Pragma("unroll")                                                      \
        for (int k = 0; k < 5; ++k)                                            \
            __builtin_amdgcn_global_load_lds(                                  \
                (gas_t)(xp + (st_ + 2 * k) * S + l * 4),                       \
                (las_t)&tile[wid][BUF][2 * k][0], 16, 0, 0);                   \
    }

#define WAITV                                                                  \
    asm volatile("s_waitcnt vmcnt(0)" ::: "memory");                           \
    __builtin_amdgcn_sched_barrier(0);

#define DSREAD(I, BUF)                                                         \
    {                                                                          \
        const int r0_    = Q0 + (I) * 8;                                       \
        const int st_    = min(max(r0_ - 1, 0), S - 10);                       \
        const int rbase_ = r0_ + rg * 4;                                       \
        _Pragma("unroll")                                                      \
        for (int j = 0; j < 6; ++j) {                                          \
            int lr = min(max(rbase_ - 1 + j - st_, 0), 9);                     \
            const float4 v = *(const float4*)&tile[wid][BUF][lr][col];         \
            float lf = __shfl(v.w, (l - 1) & 63, 64);                          \
            float rf = __shfl(v.x, (l + 1) & 63, 64);                          \
            if (qc == 0)  lf = 0.f;                                            \
            if (qc == 31) rf = 0.f;                                            \
            m[j][0] = lf; m[j][1] = v.x; m[j][2] = v.y; m[j][3] = v.z;         \
            m[j][4] = v.w; m[j][5] = rf;                                       \
        }                                                                      \
        if (rbase_ == 0)     { _Pragma("unroll") for (int t = 0; t < 6; ++t) m[0][t] = 0.f; } \
        if (rbase_ + 4 == S) { _Pragma("unroll") for (int t = 0; t < 6; ++t) m[5][t] = 0.f; } \
    }

#define WLOAD(I)                                                               \
    {                                                                          \
        const int rbase_ = Q0 + (I) * 8 + rg * 4;                              \
        _Pragma("unroll")                                                      \
        for (int rq = 0; rq < 4; ++rq) {                                       \
            w1v[rq] = *(const float4*)(w1p + (rbase_ + rq) * S + col);         \
            w2v[rq] = *(const float4*)(w2p + (rbase_ + rq) * S + col);         \
        }                                                                      \
    }

#define MATH_STORE(I)                                                          \
    {                                                                          \
        const int rbase_ = Q0 + (I) * 8 + rg * 4;                              \
        float* opr = op + rbase_ * S + col;                                    \
        _Pragma("unroll")                                                      \
        for (int rq = 0; rq < 4; ++rq) {                                       \
            const float* m0 = m[rq];                                           \
            const float* m1 = m[rq + 1];                                       \
            const float* m2 = m[rq + 2];                                       \
            const float* w1a = &w1v[rq].x;                                     \
            const float* w2a = &w2v[rq].x;                                     \
            float4 o;                                                          \
            float* ov = &o.x;                                                  \
            _Pragma("unroll")                                                  \
            for (int k = 0; k < 4; ++k) {                                      \
                const float cen = m0[k];                                       \
                float d;                                                       \
                d = cen - m0[k + 1]; const float a0 = __builtin_amdgcn_exp2f(d * d * NL); \
                d = cen - m0[k + 2]; const float a1 = __builtin_amdgcn_exp2f(d * d * NL); \
                d = cen - m1[k];     const float a2 = __builtin_amdgcn_exp2f(d * d * NL); \
                d = cen - m2[k];     const float a3 = __builtin_amdgcn_exp2f(d * d * NL); \
                d = cen - m1[k + 1]; const float b0 = __builtin_amdgcn_exp2f(d * d * NL); \
                d = cen - m1[k + 2]; const float b1 = __builtin_amdgcn_exp2f(d * d * NL); \
                d = cen - m2[k + 1]; const float b2 = __builtin_amdgcn_exp2f(d * d * NL); \
                d = cen - m2[k + 2]; const float b3 = __builtin_amdgcn_exp2f(d * d * NL); \
                const float s1 = (a0 + a1) + (a2 + a3);                        \
                const float s2 = (b0 + b1) + (b2 + b3);                        \
                const float fN = fmaf(E2N, s2, fmaf(E1N, s1, C9));             \
                ov[k] = fmaf(w1a[k], fN, w2a[k] * W2C);                        \
            }                                                                  \
            *reinterpret_cast<float4*>(opr + rq * S) = o;                      \
        }                                                                      \
    }

#define SB __builtin_amdgcn_sched_barrier(0);

    // ---- 2-deep software pipeline over 4 bands ----
    STAGE(0, 0)
    WAITV
    DSREAD(0, 0)  WLOAD(0)  SB  STAGE(1, 1)  SB
    MATH_STORE(0)
    WAITV
    DSREAD(1, 1)  WLOAD(1)  SB  STAGE(2, 0)  SB
    MATH_STORE(1)
    WAITV
    DSREAD(2, 0)  WLOAD(2)  SB  STAGE(3, 1)  SB
    MATH_STORE(2)
    WAITV
    DSREAD(3, 1)  WLOAD(3)
    MATH_STORE(3)
}

extern "C" void kernel_launch(void* const* d_in, const int* in_sizes, int n_in,
                              void* d_out, int out_size, void* d_ws, size_t ws_size,
                              hipStream_t stream) {
    const float* x  = (const float*)d_in[0];
    const float* w1 = (const float*)d_in[1];
    const float* w2 = (const float*)d_in[2];
    float* out = (float*)d_out;
    pairwise_potential_kernel<<<NBLOCKS, 256, 0, stream>>>(x, w1, w2, out);
}